// Round 11
// baseline (216.310 us; speedup 1.0000x reference)
//
#include <hip/hip_runtime.h>
#include <hip/hip_bf16.h>

// Problem constants
#define B_    2
#define S_    1024
#define HID_  1024
#define H_    16
#define P_    2
#define D_    64
#define SV_   2048   // S_*P_
#define NBH_  32     // B_*H_
// SCALE * log2(e) = 0.125 * 1.4426950408889634
#define SCALE_LOG2E 0.18033688f

typedef __attribute__((ext_vector_type(8))) short short8;
typedef __attribute__((ext_vector_type(4))) float f32x4;

#if __has_builtin(__builtin_amdgcn_exp2f)
#define EXP2(x) __builtin_amdgcn_exp2f(x)
#else
#define EXP2(x) exp2f(x)
#endif

__device__ __forceinline__ unsigned short f2bf(float f) {
  union { float f; unsigned u; } v; v.f = f;
  unsigned r = v.u + 0x7fffu + ((v.u >> 16) & 1u);
  return (unsigned short)(r >> 16);
}
__device__ __forceinline__ unsigned pack_bf2(float a, float b) {
  __hip_bfloat162 h = __float22bfloat162_rn(make_float2(a, b));
  unsigned u; __builtin_memcpy(&u, &h, 4);
  return u;
}

// ---------------------------------------------------------------------------
__global__ __launch_bounds__(256) void cast_f32_bf16(
    const float* __restrict__ src, unsigned short* __restrict__ dst, int n4) {
  int i = blockIdx.x * blockDim.x + threadIdx.x;
  int stride = gridDim.x * blockDim.x;
  for (; i < n4; i += stride) {
    float4 v = ((const float4*)src)[i];
    ushort4 o;
    o.x = f2bf(v.x); o.y = f2bf(v.y); o.z = f2bf(v.z); o.w = f2bf(v.w);
    ((ushort4*)dst)[i] = o;
  }
}

// ---------------------------------------------------------------------------
// Weff[t][r=(h*128+p*64+d)][e] = sum_m A[m*32+hp] * W[m*64+d][e]
__global__ __launch_bounds__(256) void weff_kernel(
    const float* __restrict__ Wq, const float* __restrict__ Wk,
    const float* __restrict__ Wv,
    const float* __restrict__ aq, const float* __restrict__ ak,
    const float* __restrict__ av,
    unsigned short* __restrict__ Weff) {
  __shared__ float Al[16][32];
  const int d = blockIdx.x;   // 0..63
  const int t = blockIdx.y;   // 0..2
  const float* W = (t == 0) ? Wq : ((t == 1) ? Wk : Wv);
  const float* A = (t == 0) ? aq : ((t == 1) ? ak : av);
  const int tid = threadIdx.x;
  for (int idx = tid; idx < 512; idx += 256) Al[idx >> 5][idx & 31] = A[idx];
  __syncthreads();
  const int e = tid * 4;
  float wr[16][4];
#pragma unroll
  for (int m = 0; m < 16; ++m) {
    float4 v = *(const float4*)(W + (size_t)(m * 64 + d) * 1024 + e);
    wr[m][0] = v.x; wr[m][1] = v.y; wr[m][2] = v.z; wr[m][3] = v.w;
  }
  for (int hp = 0; hp < 32; ++hp) {
    float acc0 = 0.f, acc1 = 0.f, acc2 = 0.f, acc3 = 0.f;
#pragma unroll
    for (int m = 0; m < 16; ++m) {
      float al = Al[m][hp];
      acc0 += al * wr[m][0]; acc1 += al * wr[m][1];
      acc2 += al * wr[m][2]; acc3 += al * wr[m][3];
    }
    int r = (hp >> 1) * 128 + (hp & 1) * 64 + d;
    ushort4 ov;
    ov.x = f2bf(acc0); ov.y = f2bf(acc1); ov.z = f2bf(acc2); ov.w = f2bf(acc3);
    *(ushort4*)(Weff + ((size_t)t * 2048 + r) * 1024 + e) = ov;
  }
}

// ---------------------------------------------------------------------------
// Woeff[f][o*64+d] = sum_h coll[h*32+o] * Wo[f][h*64+d]   (bf16 out)
__global__ __launch_bounds__(256) void woeff_kernel(
    const float* __restrict__ Wo, const float* __restrict__ coll,
    unsigned short* __restrict__ Woeff) {
  __shared__ float wrow[1024];
  __shared__ float cl[512];
  const int f = blockIdx.x;
  const int tid = threadIdx.x;
  for (int idx = tid; idx < 512; idx += 256) cl[idx] = coll[idx];
  for (int idx = tid; idx < 1024; idx += 256) wrow[idx] = Wo[(size_t)f * 1024 + idx];
  __syncthreads();
  for (int idx = tid; idx < 2048; idx += 256) {
    int o = idx >> 6, d = idx & 63;
    float acc = 0.f;
#pragma unroll
    for (int h = 0; h < 16; ++h) acc += wrow[h * 64 + d] * cl[h * 32 + o];
    Woeff[(size_t)f * 2048 + idx] = f2bf(acc);
  }
}

// ---------------------------------------------------------------------------
// 128x128 bf16 GEMM, C[row,col] = sum_k A[row,k]*Bmat[col,k], pipelined.
// OUTMODE 0: Q/K scatter epilogue (blockIdx.z = 0 Q, 1 K)
// OUTMODE 2: V^T epilogue — here A = Weff_v (rows = h,p,d), B = X (rows = b,n);
//            C rows are (h,p,d), cols are (b,n) -> Vt[(b,h,d)][n*2+p] stores
//            are n-major (stride 4B), ~4 lines per store instr.
template <int OUTMODE>
__global__ __launch_bounds__(256) void gemm_bt(
    const unsigned short* __restrict__ A,
    const unsigned short* __restrict__ Bbase,
    int M, int N, int K,
    unsigned short* __restrict__ Qd, unsigned short* __restrict__ Kd,
    unsigned short* __restrict__ Vd) {
  __shared__ unsigned short As[2][128 * 32];
  __shared__ unsigned short Bs[2][128 * 32];
  const int t = threadIdx.x;
  const int wave = t >> 6, lane = t & 63, lrow = lane & 15, quad = lane >> 4;
  const int wm = wave >> 1, wn = wave & 1;
  const int row0 = blockIdx.x * 128;
  const int col0 = blockIdx.y * 128;
  const unsigned short* Ap = A;
  if (OUTMODE == 0) Ap += 0;  // A is Xb
  const unsigned short* Bp = Bbase;
  if (OUTMODE == 0) Bp += (size_t)blockIdx.z * 2048 * 1024;

  const int r16 = lane >> 2;
  const int gc = (lane & 3) * 8;

  auto stage = [&](int k0, int buf) {
#pragma unroll
    for (int j = 0; j < 2; ++j) {
      const int cc = wave * 2 + j;  // wave-uniform 16-row chunk
      const unsigned short* ga = Ap + (size_t)(row0 + cc * 16 + r16) * K + k0 + gc;
      __builtin_amdgcn_global_load_lds(
          (const __attribute__((address_space(1))) unsigned int*)ga,
          (__attribute__((address_space(3))) unsigned int*)(&As[buf][cc * 512]), 16, 0, 0);
      const unsigned short* gb = Bp + (size_t)(col0 + cc * 16 + r16) * K + k0 + gc;
      __builtin_amdgcn_global_load_lds(
          (const __attribute__((address_space(1))) unsigned int*)gb,
          (__attribute__((address_space(3))) unsigned int*)(&Bs[buf][cc * 512]), 16, 0, 0);
    }
  };

  f32x4 acc[4][4];
#pragma unroll
  for (int mi = 0; mi < 4; ++mi)
#pragma unroll
    for (int ni = 0; ni < 4; ++ni) acc[mi][ni] = (f32x4){0.f, 0.f, 0.f, 0.f};

  const int niter = K >> 5;
  stage(0, 0);

  for (int it = 0; it < niter; ++it) {
    const int buf = it & 1;
    if (it + 1 < niter) {
      stage((it + 1) * 32, buf ^ 1);
      asm volatile("s_waitcnt vmcnt(4)" ::: "memory");
    } else {
      asm volatile("s_waitcnt vmcnt(0)" ::: "memory");
    }
    asm volatile("s_barrier" ::: "memory");

    short8 af[4], bfr[4];
#pragma unroll
    for (int mi = 0; mi < 4; ++mi)
      af[mi] = *(const short8*)(&As[buf][(wm * 64 + mi * 16 + lrow) * 32 + quad * 8]);
#pragma unroll
    for (int ni = 0; ni < 4; ++ni)
      bfr[ni] = *(const short8*)(&Bs[buf][(wn * 64 + ni * 16 + lrow) * 32 + quad * 8]);
#pragma unroll
    for (int mi = 0; mi < 4; ++mi)
#pragma unroll
      for (int ni = 0; ni < 4; ++ni)
        acc[mi][ni] = __builtin_amdgcn_mfma_f32_16x16x32_bf16(af[mi], bfr[ni],
                                                              acc[mi][ni], 0, 0, 0);

    asm volatile("s_barrier" ::: "memory");
  }

#pragma unroll
  for (int mi = 0; mi < 4; ++mi) {
#pragma unroll
    for (int ni = 0; ni < 4; ++ni) {
#pragma unroll
      for (int i = 0; i < 4; ++i) {
        int grow = row0 + wm * 64 + mi * 16 + quad * 4 + i;
        int gcol = col0 + wn * 64 + ni * 16 + lrow;
        float val = acc[mi][ni][i];
        if (OUTMODE == 0) {
          int b = grow >> 10, n = grow & 1023;
          int h = gcol >> 7, p = (gcol >> 6) & 1, d = gcol & 63;
          unsigned short* dst = (blockIdx.z == 0) ? Qd : Kd;
          dst[((size_t)((b * 16 + h) * 2048) + n * 2 + p) * 64 + d] = f2bf(val);
        } else {
          // grow = (h,p,d), gcol = (b, n)
          int h = grow >> 7, p = (grow >> 6) & 1, d = grow & 63;
          int b = gcol >> 10, n = gcol & 1023;
          Vd[((size_t)((b * 16 + h) * 64 + d)) * 2048 + n * 2 + p] = f2bf(val);
        }
      }
    }
  }
}

// ---------------------------------------------------------------------------
// 64x128 bf16 GEMM (full-GPU grid for M=2048,N=1024): wave w owns 32-col strip.
__global__ __launch_bounds__(256) void gemm64(
    const unsigned short* __restrict__ A,
    const unsigned short* __restrict__ Bbase,
    int M, int N, int K, float* __restrict__ Cf) {
  __shared__ unsigned short As[2][64 * 32];
  __shared__ unsigned short Bs[2][128 * 32];
  const int t = threadIdx.x;
  const int wave = t >> 6, lane = t & 63, lrow = lane & 15, quad = lane >> 4;
  const int row0 = blockIdx.x * 64;
  const int col0 = blockIdx.y * 128;

  const int r16 = lane >> 2;
  const int gc = (lane & 3) * 8;

  auto stage = [&](int k0, int buf) {
    // A: 4 chunks of 16 rows; wave w stages chunk w
    const unsigned short* ga = A + (size_t)(row0 + wave * 16 + r16) * K + k0 + gc;
    __builtin_amdgcn_global_load_lds(
        (const __attribute__((address_space(1))) unsigned int*)ga,
        (__attribute__((address_space(3))) unsigned int*)(&As[buf][wave * 512]), 16, 0, 0);
    // B: 8 chunks; wave w stages chunks 2w, 2w+1
#pragma unroll
    for (int j = 0; j < 2; ++j) {
      const int cc = wave * 2 + j;
      const unsigned short* gb = Bbase + (size_t)(col0 + cc * 16 + r16) * K + k0 + gc;
      __builtin_amdgcn_global_load_lds(
          (const __attribute__((address_space(1))) unsigned int*)gb,
          (__attribute__((address_space(3))) unsigned int*)(&Bs[buf][cc * 512]), 16, 0, 0);
    }
  };

  f32x4 acc[4][2];
#pragma unroll
  for (int mi = 0; mi < 4; ++mi)
#pragma unroll
    for (int ni = 0; ni < 2; ++ni) acc[mi][ni] = (f32x4){0.f, 0.f, 0.f, 0.f};

  const int niter = K >> 5;
  stage(0, 0);

  for (int it = 0; it < niter; ++it) {
    const int buf = it & 1;
    if (it + 1 < niter) {
      stage((it + 1) * 32, buf ^ 1);
      asm volatile("s_waitcnt vmcnt(3)" ::: "memory");
    } else {
      asm volatile("s_waitcnt vmcnt(0)" ::: "memory");
    }
    asm volatile("s_barrier" ::: "memory");

    short8 af[4], bfr[2];
#pragma unroll
    for (int mi = 0; mi < 4; ++mi)
      af[mi] = *(const short8*)(&As[buf][(mi * 16 + lrow) * 32 + quad * 8]);
#pragma unroll
    for (int ni = 0; ni < 2; ++ni)
      bfr[ni] = *(const short8*)(&Bs[buf][(wave * 32 + ni * 16 + lrow) * 32 + quad * 8]);
#pragma unroll
    for (int mi = 0; mi < 4; ++mi)
#pragma unroll
      for (int ni = 0; ni < 2; ++ni)
        acc[mi][ni] = __builtin_amdgcn_mfma_f32_16x16x32_bf16(af[mi], bfr[ni],
                                                              acc[mi][ni], 0, 0, 0);

    asm volatile("s_barrier" ::: "memory");
  }

#pragma unroll
  for (int mi = 0; mi < 4; ++mi)
#pragma unroll
    for (int ni = 0; ni < 2; ++ni)
#pragma unroll
      for (int i = 0; i < 4; ++i) {
        int grow = row0 + mi * 16 + quad * 4 + i;
        int gcol = col0 + wave * 32 + ni * 16 + lrow;
        Cf[(size_t)grow * N + gcol] = acc[mi][ni][i];
      }
}

// ---------------------------------------------------------------------------
// Causal flash attention, S^T form. 64 q-rows/block (wave = 16 q-rows),
// grid (32 bh, 32 y), qt = y<16 ? y : 47-y: every co-resident 4-set
// {y,y+8,y+16,y+24} sums to 66 tiles (uniform), all share bh (L2 reuse).
// LDS 40 KB -> 4 blocks/CU (16 waves). Double-buffered K/V via
// global_load_lds; raw s_barrier + vmcnt(4); XOR-swizzled granules.
__global__ __launch_bounds__(256, 4) void attn_kernel(
    const unsigned short* __restrict__ Qv, const unsigned short* __restrict__ Kv,
    const unsigned short* __restrict__ Vt, unsigned short* __restrict__ Aov) {
  __shared__ unsigned short Ks[2][4096];   // [buf][row 64][col 64] swizzled
  __shared__ unsigned short Vs[2][4096];   // [buf][d 64][kcol 64] swizzled
  __shared__ unsigned short Plds[4][1024]; // per wave [q 16][kcol 64] swizzled
  const int bh = blockIdx.x;
  const int yy = blockIdx.y;
  const int qt = (yy < 16) ? yy : (47 - yy);
  const int t = threadIdx.x;
  const int w = t >> 6, lane = t & 63, lq = lane & 15, quad = lane >> 4;
  const int l3 = lq & 7;

  const unsigned short* Qh = Qv + (size_t)bh * SV_ * D_;
  const unsigned short* Kh = Kv + (size_t)bh * SV_ * D_;
  const unsigned short* Vh = Vt + (size_t)bh * D_ * SV_;

  const int qrow = qt * 64 + w * 16 + lq;  // this lane's q row
  short8 bq0 = *(const short8*)(Qh + (size_t)qrow * 64 + quad * 8);
  short8 bq1 = *(const short8*)(Qh + (size_t)qrow * 64 + 32 + quad * 8);

  // Staging: lane-linear LDS granules; global side applies the XOR swizzle.
  const int sg = (lane & 7) ^ ((lane >> 3) & 7);  // granule ^ (row&7)
  const int r0 = w * 16 + (lane >> 3);            // row for issue 0 (+8 for issue 1)
  const unsigned short* Kg0 = Kh + r0 * 64 + sg * 8;
  const unsigned short* Vg0 = Vh + (size_t)r0 * SV_ + sg * 8;
  const int lds0 = w * 1024;       // shorts (16 rows x 64), wave-uniform
  const int lds1 = lds0 + 512;     // +8 rows

  auto stage = [&](int kt) {
    const int buf = kt & 1;
    const unsigned short* kg = Kg0 + kt * 4096;
    const unsigned short* vg = Vg0 + kt * 64;
    __builtin_amdgcn_global_load_lds(
        (const __attribute__((address_space(1))) unsigned int*)kg,
        (__attribute__((address_space(3))) unsigned int*)(&Ks[buf][lds0]), 16, 0, 0);
    __builtin_amdgcn_global_load_lds(
        (const __attribute__((address_space(1))) unsigned int*)(kg + 8 * 64),
        (__attribute__((address_space(3))) unsigned int*)(&Ks[buf][lds1]), 16, 0, 0);
    __builtin_amdgcn_global_load_lds(
        (const __attribute__((address_space(1))) unsigned int*)vg,
        (__attribute__((address_space(3))) unsigned int*)(&Vs[buf][lds0]), 16, 0, 0);
    __builtin_amdgcn_global_load_lds(
        (const __attribute__((address_space(1))) unsigned int*)(vg + (size_t)8 * SV_),
        (__attribute__((address_space(3))) unsigned int*)(&Vs[buf][lds1]), 16, 0, 0);
  };

  unsigned short* Pw = Plds[w];

  float l_sum = 0.f;
  f32x4 o_acc[4];
#pragma unroll
  for (int nd = 0; nd < 4; ++nd) o_acc[nd] = (f32x4){0.f, 0.f, 0.f, 0.f};

  const int nt = qt + 1;
  stage(0);

  for (int kt = 0; kt < nt; ++kt) {
    const int buf = kt & 1;
    if (kt + 1 < nt) {
      stage(kt + 1);
      asm volatile("s_waitcnt vmcnt(4)" ::: "memory");
    } else {
      asm volatile("s_waitcnt vmcnt(0)" ::: "memory");
    }
    asm volatile("s_barrier" ::: "memory");

    // ---- K fragments from LDS ----
    const unsigned short* Kb = Ks[buf];
    short8 ka[4][2];
#pragma unroll
    for (int t4 = 0; t4 < 4; ++t4)
#pragma unroll
      for (int c = 0; c < 2; ++c)
        ka[t4][c] = *(const short8*)(Kb + (t4 * 16 + lq) * 64 + (((c * 4 + quad) ^ l3) * 8));

    // ---- S^T = K·Q^T ----
    f32x4 s[4];
#pragma unroll
    for (int t4 = 0; t4 < 4; ++t4) {
      f32x4 z = (f32x4){0.f, 0.f, 0.f, 0.f};
      z = __builtin_amdgcn_mfma_f32_16x16x32_bf16(ka[t4][0], bq0, z, 0, 0, 0);
      s[t4] = __builtin_amdgcn_mfma_f32_16x16x32_bf16(ka[t4][1], bq1, s[t4] = z, 0, 0, 0);
    }

    // ---- p = exp2(s*c), diagonal mask, in-lane row-sum, P->LDS ----
    const bool diag = (kt == qt);
    const int kc0 = kt * 64 + quad * 4;
    float rs = 0.f;
#pragma unroll
    for (int t4 = 0; t4 < 4; ++t4) {
      float p[4];
#pragma unroll
      for (int i = 0; i < 4; ++i) {
        float e = EXP2(s[t4][i] * SCALE_LOG2E);
        if (diag) e = (kc0 + t4 * 16 + i > qrow) ? 0.f : e;
        p[i] = e;
        rs += e;
      }
      uint2 dw;
      dw.x = pack_bf2(p[0], p[1]);
      dw.y = pack_bf2(p[2], p[3]);
      const int cg = t4 * 2 + (quad >> 1);
      *(uint2*)(Pw + lq * 64 + ((cg ^ l3) * 8) + (quad & 1) * 4) = dw;
    }
    l_sum += rs;

    // ---- O^T += V^T · P^T ----
    const unsigned short* Vb = Vs[buf];
#pragma unroll
    for (int kh = 0; kh < 2; ++kh) {
      short8 bp = *(const short8*)(Pw + lq * 64 + (((kh * 4 + quad) ^ l3) * 8));
#pragma unroll
      for (int nd = 0; nd < 4; ++nd) {
        short8 va = *(const short8*)(Vb + (nd * 16 + lq) * 64 + (((kh * 4 + quad) ^ l3) * 8));
        o_acc[nd] = __builtin_amdgcn_mfma_f32_16x16x32_bf16(va, bp, o_acc[nd], 0, 0, 0);
      }
    }

    asm volatile("s_barrier" ::: "memory");
  }

  // final cross-quad row-sum reduction
  l_sum += __shfl_xor(l_sum, 16);
  l_sum += __shfl_xor(l_sum, 32);

  const int b = bh >> 4, h = bh & 15;
  const float inv = 1.0f / l_sum;
  const int n = qrow >> 1, p = qrow & 1;
  unsigned short* dst = Aov + ((size_t)(b * 1024 + n)) * 2048 + (h * 2 + p) * 64;
#pragma unroll
  for (int nd = 0; nd < 4; ++nd) {
    uint2 dw;
    dw.x = pack_bf2(o_acc[nd][0] * inv, o_acc[nd][1] * inv);
    dw.y = pack_bf2(o_acc[nd][2] * inv, o_acc[nd][3] * inv);
    *(uint2*)(dst + nd * 16 + quad * 4) = dw;
  }
}

// ---------------------------------------------------------------------------
extern "C" void kernel_launch(void* const* d_in, const int* in_sizes, int n_in,
                              void* d_out, int out_size, void* d_ws, size_t ws_size,
                              hipStream_t stream) {
  (void)in_sizes; (void)n_in; (void)out_size; (void)ws_size;
  const float* x    = (const float*)d_in[0];
  const float* Wq   = (const float*)d_in[1];
  const float* Wk   = (const float*)d_in[2];
  const float* Wv   = (const float*)d_in[3];
  const float* Wo   = (const float*)d_in[4];
  const float* aq   = (const float*)d_in[5];
  const float* ak   = (const float*)d_in[6];
  const float* av   = (const float*)d_in[7];
  const float* coll = (const float*)d_in[8];
  float* out = (float*)d_out;

  char* ws = (char*)d_ws;
  const size_t MB = 1024 * 1024;
  unsigned short* Xb    = (unsigned short*)(ws);            // 4 MB  [0,4)
  unsigned short* Woeff = (unsigned short*)(ws + 4 * MB);   // 4 MB  [4,8)
  unsigned short* Weff  = (unsigned short*)(ws + 8 * MB);   // 12 MB [8,20)
  unsigned short* Qv    = (unsigned short*)(ws + 20 * MB);  // 8 MB  [20,28)
  unsigned short* Kv    = (unsigned short*)(ws + 28 * MB);  // 8 MB  [28,36)
  unsigned short* Vt    = (unsigned short*)(ws + 36 * MB);  // 8 MB  [36,44)
  // Weff dead after QKV GEMMs; reuse:
  unsigned short* Aov   = (unsigned short*)(ws + 8 * MB);   // 8 MB  [8,16)

  cast_f32_bf16<<<dim3(1024), dim3(256), 0, stream>>>(x, Xb, (B_ * S_ * HID_) / 4);
  weff_kernel<<<dim3(64, 3), dim3(256), 0, stream>>>(Wq, Wk, Wv, aq, ak, av, Weff);
  gemm_bt<0><<<dim3(16, 16, 2), dim3(256), 0, stream>>>(
      Xb, Weff, 2048, 2048, 1024, Qv, Kv, nullptr);
  gemm_bt<2><<<dim3(16, 16), dim3(256), 0, stream>>>(
      Weff + (size_t)2 * 2048 * 1024, Xb, 2048, 2048, 1024, nullptr, nullptr, Vt);
  attn_kernel<<<dim3(32, 32), dim3(256), 0, stream>>>(Qv, Kv, Vt, Aov);
  woeff_kernel<<<dim3(1024), dim3(256), 0, stream>>>(Wo, coll, Woeff);
  gemm64<<<dim3(32, 8), dim3(256), 0, stream>>>(
      Aov, Woeff, 2048, 1024, 2048, out);
}

// Round 12
// 207.779 us; speedup vs baseline: 1.0411x; 1.0411x over previous
//
#include <hip/hip_runtime.h>
#include <hip/hip_bf16.h>

// Problem constants
#define B_    2
#define S_    1024
#define HID_  1024
#define H_    16
#define P_    2
#define D_    64
#define SV_   2048   // S_*P_
#define NBH_  32     // B_*H_
// SCALE * log2(e) = 0.125 * 1.4426950408889634
#define SCALE_LOG2E 0.18033688f

typedef __attribute__((ext_vector_type(8))) short short8;
typedef __attribute__((ext_vector_type(4))) float f32x4;

#if __has_builtin(__builtin_amdgcn_exp2f)
#define EXP2(x) __builtin_amdgcn_exp2f(x)
#else
#define EXP2(x) exp2f(x)
#endif

__device__ __forceinline__ unsigned short f2bf(float f) {
  union { float f; unsigned u; } v; v.f = f;
  unsigned r = v.u + 0x7fffu + ((v.u >> 16) & 1u);
  return (unsigned short)(r >> 16);
}
__device__ __forceinline__ unsigned pack_bf2(float a, float b) {
  __hip_bfloat162 h = __float22bfloat162_rn(make_float2(a, b));
  unsigned u; __builtin_memcpy(&u, &h, 4);
  return u;
}

// ---------------------------------------------------------------------------
__global__ __launch_bounds__(256) void cast_f32_bf16(
    const float* __restrict__ src, unsigned short* __restrict__ dst, int n4) {
  int i = blockIdx.x * blockDim.x + threadIdx.x;
  int stride = gridDim.x * blockDim.x;
  for (; i < n4; i += stride) {
    float4 v = ((const float4*)src)[i];
    ushort4 o;
    o.x = f2bf(v.x); o.y = f2bf(v.y); o.z = f2bf(v.z); o.w = f2bf(v.w);
    ((ushort4*)dst)[i] = o;
  }
}

// ---------------------------------------------------------------------------
// Weff[t][r=(h*128+p*64+d)][e] = sum_m A[m*32+hp] * W[m*64+d][e]
__global__ __launch_bounds__(256) void weff_kernel(
    const float* __restrict__ Wq, const float* __restrict__ Wk,
    const float* __restrict__ Wv,
    const float* __restrict__ aq, const float* __restrict__ ak,
    const float* __restrict__ av,
    unsigned short* __restrict__ Weff) {
  __shared__ float Al[16][32];
  const int d = blockIdx.x;   // 0..63
  const int t = blockIdx.y;   // 0..2
  const float* W = (t == 0) ? Wq : ((t == 1) ? Wk : Wv);
  const float* A = (t == 0) ? aq : ((t == 1) ? ak : av);
  const int tid = threadIdx.x;
  for (int idx = tid; idx < 512; idx += 256) Al[idx >> 5][idx & 31] = A[idx];
  __syncthreads();
  const int e = tid * 4;
  float wr[16][4];
#pragma unroll
  for (int m = 0; m < 16; ++m) {
    float4 v = *(const float4*)(W + (size_t)(m * 64 + d) * 1024 + e);
    wr[m][0] = v.x; wr[m][1] = v.y; wr[m][2] = v.z; wr[m][3] = v.w;
  }
  for (int hp = 0; hp < 32; ++hp) {
    float acc0 = 0.f, acc1 = 0.f, acc2 = 0.f, acc3 = 0.f;
#pragma unroll
    for (int m = 0; m < 16; ++m) {
      float al = Al[m][hp];
      acc0 += al * wr[m][0]; acc1 += al * wr[m][1];
      acc2 += al * wr[m][2]; acc3 += al * wr[m][3];
    }
    int r = (hp >> 1) * 128 + (hp & 1) * 64 + d;
    ushort4 ov;
    ov.x = f2bf(acc0); ov.y = f2bf(acc1); ov.z = f2bf(acc2); ov.w = f2bf(acc3);
    *(ushort4*)(Weff + ((size_t)t * 2048 + r) * 1024 + e) = ov;
  }
}

// ---------------------------------------------------------------------------
// Woeff[f][o*64+d] = sum_h coll[h*32+o] * Wo[f][h*64+d]   (bf16 out)
__global__ __launch_bounds__(256) void woeff_kernel(
    const float* __restrict__ Wo, const float* __restrict__ coll,
    unsigned short* __restrict__ Woeff) {
  __shared__ float wrow[1024];
  __shared__ float cl[512];
  const int f = blockIdx.x;
  const int tid = threadIdx.x;
  for (int idx = tid; idx < 512; idx += 256) cl[idx] = coll[idx];
  for (int idx = tid; idx < 1024; idx += 256) wrow[idx] = Wo[(size_t)f * 1024 + idx];
  __syncthreads();
  for (int idx = tid; idx < 2048; idx += 256) {
    int o = idx >> 6, d = idx & 63;
    float acc = 0.f;
#pragma unroll
    for (int h = 0; h < 16; ++h) acc += wrow[h * 64 + d] * cl[h * 32 + o];
    Woeff[(size_t)f * 2048 + idx] = f2bf(acc);
  }
}

// ---------------------------------------------------------------------------
// Unified QKV GEMM (SINGLE change vs round-11: z=0/1/2 in one launch).
// 128x128 tile, BK=32, pipelined, grid (16,16,3) = 768 blocks = 3/CU.
// z=0: Q = Xb·Weff_q^T -> Qv[(b,h,v),d];  z=1: K likewise;
// z=2: V^T = Weff_v·Xb^T -> Vt[(b,h,d),v] (n-major stores).
__global__ __launch_bounds__(256) void qkv_gemm(
    const unsigned short* __restrict__ Xb,
    const unsigned short* __restrict__ Weff,
    unsigned short* __restrict__ Qd, unsigned short* __restrict__ Kd,
    unsigned short* __restrict__ Vd) {
  __shared__ unsigned short As[2][128 * 32];
  __shared__ unsigned short Bs[2][128 * 32];
  const int K = 1024;
  const int t = threadIdx.x;
  const int wave = t >> 6, lane = t & 63, lrow = lane & 15, quad = lane >> 4;
  const int wm = wave >> 1, wn = wave & 1;
  const int row0 = blockIdx.x * 128;
  const int col0 = blockIdx.y * 128;
  const int z = blockIdx.z;
  const unsigned short* Ap = (z == 2) ? (Weff + (size_t)2 * 2048 * 1024) : Xb;
  const unsigned short* Bp = (z == 2) ? Xb : (Weff + (size_t)z * 2048 * 1024);

  const int r16 = lane >> 2;
  const int gc = (lane & 3) * 8;

  auto stage = [&](int k0, int buf) {
#pragma unroll
    for (int j = 0; j < 2; ++j) {
      const int cc = wave * 2 + j;  // wave-uniform 16-row chunk
      const unsigned short* ga = Ap + (size_t)(row0 + cc * 16 + r16) * K + k0 + gc;
      __builtin_amdgcn_global_load_lds(
          (const __attribute__((address_space(1))) unsigned int*)ga,
          (__attribute__((address_space(3))) unsigned int*)(&As[buf][cc * 512]), 16, 0, 0);
      const unsigned short* gb = Bp + (size_t)(col0 + cc * 16 + r16) * K + k0 + gc;
      __builtin_amdgcn_global_load_lds(
          (const __attribute__((address_space(1))) unsigned int*)gb,
          (__attribute__((address_space(3))) unsigned int*)(&Bs[buf][cc * 512]), 16, 0, 0);
    }
  };

  f32x4 acc[4][4];
#pragma unroll
  for (int mi = 0; mi < 4; ++mi)
#pragma unroll
    for (int ni = 0; ni < 4; ++ni) acc[mi][ni] = (f32x4){0.f, 0.f, 0.f, 0.f};

  const int niter = K >> 5;
  stage(0, 0);

  for (int it = 0; it < niter; ++it) {
    const int buf = it & 1;
    if (it + 1 < niter) {
      stage((it + 1) * 32, buf ^ 1);
      asm volatile("s_waitcnt vmcnt(4)" ::: "memory");
    } else {
      asm volatile("s_waitcnt vmcnt(0)" ::: "memory");
    }
    asm volatile("s_barrier" ::: "memory");

    short8 af[4], bfr[4];
#pragma unroll
    for (int mi = 0; mi < 4; ++mi)
      af[mi] = *(const short8*)(&As[buf][(wm * 64 + mi * 16 + lrow) * 32 + quad * 8]);
#pragma unroll
    for (int ni = 0; ni < 4; ++ni)
      bfr[ni] = *(const short8*)(&Bs[buf][(wn * 64 + ni * 16 + lrow) * 32 + quad * 8]);
#pragma unroll
    for (int mi = 0; mi < 4; ++mi)
#pragma unroll
      for (int ni = 0; ni < 4; ++ni)
        acc[mi][ni] = __builtin_amdgcn_mfma_f32_16x16x32_bf16(af[mi], bfr[ni],
                                                              acc[mi][ni], 0, 0, 0);

    asm volatile("s_barrier" ::: "memory");
  }

#pragma unroll
  for (int mi = 0; mi < 4; ++mi) {
#pragma unroll
    for (int ni = 0; ni < 4; ++ni) {
#pragma unroll
      for (int i = 0; i < 4; ++i) {
        int grow = row0 + wm * 64 + mi * 16 + quad * 4 + i;
        int gcol = col0 + wn * 64 + ni * 16 + lrow;
        float val = acc[mi][ni][i];
        if (z != 2) {
          int b = grow >> 10, n = grow & 1023;
          int h = gcol >> 7, p = (gcol >> 6) & 1, d = gcol & 63;
          unsigned short* dst = (z == 0) ? Qd : Kd;
          dst[((size_t)((b * 16 + h) * 2048) + n * 2 + p) * 64 + d] = f2bf(val);
        } else {
          // grow = (h,p,d), gcol = (b, n)
          int h = grow >> 7, p = (grow >> 6) & 1, d = grow & 63;
          int b = gcol >> 10, n = gcol & 1023;
          Vd[((size_t)((b * 16 + h) * 64 + d)) * 2048 + n * 2 + p] = f2bf(val);
        }
      }
    }
  }
}

// ---------------------------------------------------------------------------
// 64x128 bf16 GEMM (full-GPU grid for M=2048,N=1024): wave w owns 32-col strip.
__global__ __launch_bounds__(256) void gemm64(
    const unsigned short* __restrict__ A,
    const unsigned short* __restrict__ Bbase,
    int M, int N, int K, float* __restrict__ Cf) {
  __shared__ unsigned short As[2][64 * 32];
  __shared__ unsigned short Bs[2][128 * 32];
  const int t = threadIdx.x;
  const int wave = t >> 6, lane = t & 63, lrow = lane & 15, quad = lane >> 4;
  const int row0 = blockIdx.x * 64;
  const int col0 = blockIdx.y * 128;

  const int r16 = lane >> 2;
  const int gc = (lane & 3) * 8;

  auto stage = [&](int k0, int buf) {
    // A: 4 chunks of 16 rows; wave w stages chunk w
    const unsigned short* ga = A + (size_t)(row0 + wave * 16 + r16) * K + k0 + gc;
    __builtin_amdgcn_global_load_lds(
        (const __attribute__((address_space(1))) unsigned int*)ga,
        (__attribute__((address_space(3))) unsigned int*)(&As[buf][wave * 512]), 16, 0, 0);
    // B: 8 chunks; wave w stages chunks 2w, 2w+1
#pragma unroll
    for (int j = 0; j < 2; ++j) {
      const int cc = wave * 2 + j;
      const unsigned short* gb = Bbase + (size_t)(col0 + cc * 16 + r16) * K + k0 + gc;
      __builtin_amdgcn_global_load_lds(
          (const __attribute__((address_space(1))) unsigned int*)gb,
          (__attribute__((address_space(3))) unsigned int*)(&Bs[buf][cc * 512]), 16, 0, 0);
    }
  };

  f32x4 acc[4][2];
#pragma unroll
  for (int mi = 0; mi < 4; ++mi)
#pragma unroll
    for (int ni = 0; ni < 2; ++ni) acc[mi][ni] = (f32x4){0.f, 0.f, 0.f, 0.f};

  const int niter = K >> 5;
  stage(0, 0);

  for (int it = 0; it < niter; ++it) {
    const int buf = it & 1;
    if (it + 1 < niter) {
      stage((it + 1) * 32, buf ^ 1);
      asm volatile("s_waitcnt vmcnt(3)" ::: "memory");
    } else {
      asm volatile("s_waitcnt vmcnt(0)" ::: "memory");
    }
    asm volatile("s_barrier" ::: "memory");

    short8 af[4], bfr[2];
#pragma unroll
    for (int mi = 0; mi < 4; ++mi)
      af[mi] = *(const short8*)(&As[buf][(mi * 16 + lrow) * 32 + quad * 8]);
#pragma unroll
    for (int ni = 0; ni < 2; ++ni)
      bfr[ni] = *(const short8*)(&Bs[buf][(wave * 32 + ni * 16 + lrow) * 32 + quad * 8]);
#pragma unroll
    for (int mi = 0; mi < 4; ++mi)
#pragma unroll
      for (int ni = 0; ni < 2; ++ni)
        acc[mi][ni] = __builtin_amdgcn_mfma_f32_16x16x32_bf16(af[mi], bfr[ni],
                                                              acc[mi][ni], 0, 0, 0);

    asm volatile("s_barrier" ::: "memory");
  }

#pragma unroll
  for (int mi = 0; mi < 4; ++mi)
#pragma unroll
    for (int ni = 0; ni < 2; ++ni)
#pragma unroll
      for (int i = 0; i < 4; ++i) {
        int grow = row0 + mi * 16 + quad * 4 + i;
        int gcol = col0 + wave * 32 + ni * 16 + lrow;
        Cf[(size_t)grow * N + gcol] = acc[mi][ni][i];
      }
}

// ---------------------------------------------------------------------------
// Causal flash attention, S^T form. 64 q-rows/block (wave = 16 q-rows),
// grid (32 bh, 32 y), qt = y<16 ? y : 47-y: every co-resident 4-set
// {y,y+8,y+16,y+24} sums to 66 tiles (uniform), all share bh (L2 reuse).
// LDS 40 KB -> 4 blocks/CU (16 waves). Double-buffered K/V via
// global_load_lds; raw s_barrier + vmcnt(4); XOR-swizzled granules.
__global__ __launch_bounds__(256, 4) void attn_kernel(
    const unsigned short* __restrict__ Qv, const unsigned short* __restrict__ Kv,
    const unsigned short* __restrict__ Vt, unsigned short* __restrict__ Aov) {
  __shared__ unsigned short Ks[2][4096];   // [buf][row 64][col 64] swizzled
  __shared__ unsigned short Vs[2][4096];   // [buf][d 64][kcol 64] swizzled
  __shared__ unsigned short Plds[4][1024]; // per wave [q 16][kcol 64] swizzled
  const int bh = blockIdx.x;
  const int yy = blockIdx.y;
  const int qt = (yy < 16) ? yy : (47 - yy);
  const int t = threadIdx.x;
  const int w = t >> 6, lane = t & 63, lq = lane & 15, quad = lane >> 4;
  const int l3 = lq & 7;

  const unsigned short* Qh = Qv + (size_t)bh * SV_ * D_;
  const unsigned short* Kh = Kv + (size_t)bh * SV_ * D_;
  const unsigned short* Vh = Vt + (size_t)bh * D_ * SV_;

  const int qrow = qt * 64 + w * 16 + lq;  // this lane's q row
  short8 bq0 = *(const short8*)(Qh + (size_t)qrow * 64 + quad * 8);
  short8 bq1 = *(const short8*)(Qh + (size_t)qrow * 64 + 32 + quad * 8);

  // Staging: lane-linear LDS granules; global side applies the XOR swizzle.
  const int sg = (lane & 7) ^ ((lane >> 3) & 7);  // granule ^ (row&7)
  const int r0 = w * 16 + (lane >> 3);            // row for issue 0 (+8 for issue 1)
  const unsigned short* Kg0 = Kh + r0 * 64 + sg * 8;
  const unsigned short* Vg0 = Vh + (size_t)r0 * SV_ + sg * 8;
  const int lds0 = w * 1024;       // shorts (16 rows x 64), wave-uniform
  const int lds1 = lds0 + 512;     // +8 rows

  auto stage = [&](int kt) {
    const int buf = kt & 1;
    const unsigned short* kg = Kg0 + kt * 4096;
    const unsigned short* vg = Vg0 + kt * 64;
    __builtin_amdgcn_global_load_lds(
        (const __attribute__((address_space(1))) unsigned int*)kg,
        (__attribute__((address_space(3))) unsigned int*)(&Ks[buf][lds0]), 16, 0, 0);
    __builtin_amdgcn_global_load_lds(
        (const __attribute__((address_space(1))) unsigned int*)(kg + 8 * 64),
        (__attribute__((address_space(3))) unsigned int*)(&Ks[buf][lds1]), 16, 0, 0);
    __builtin_amdgcn_global_load_lds(
        (const __attribute__((address_space(1))) unsigned int*)vg,
        (__attribute__((address_space(3))) unsigned int*)(&Vs[buf][lds0]), 16, 0, 0);
    __builtin_amdgcn_global_load_lds(
        (const __attribute__((address_space(1))) unsigned int*)(vg + (size_t)8 * SV_),
        (__attribute__((address_space(3))) unsigned int*)(&Vs[buf][lds1]), 16, 0, 0);
  };

  unsigned short* Pw = Plds[w];

  float l_sum = 0.f;
  f32x4 o_acc[4];
#pragma unroll
  for (int nd = 0; nd < 4; ++nd) o_acc[nd] = (f32x4){0.f, 0.f, 0.f, 0.f};

  const int nt = qt + 1;
  stage(0);

  for (int kt = 0; kt < nt; ++kt) {
    const int buf = kt & 1;
    if (kt + 1 < nt) {
      stage(kt + 1);
      asm volatile("s_waitcnt vmcnt(4)" ::: "memory");
    } else {
      asm volatile("s_waitcnt vmcnt(0)" ::: "memory");
    }
    asm volatile("s_barrier" ::: "memory");

    // ---- K fragments from LDS ----
    const unsigned short* Kb = Ks[buf];
    short8 ka[4][2];
#pragma unroll
    for (int t4 = 0; t4 < 4; ++t4)
#pragma unroll
      for (int c = 0; c < 2; ++c)
        ka[t4][c] = *(const short8*)(Kb + (t4 * 16 + lq) * 64 + (((c * 4 + quad) ^ l3) * 8));

    // ---- S^T = K·Q^T ----
    f32x4 s[4];
#pragma unroll
    for (int t4 = 0; t4 < 4; ++t4) {
      f32x4 z = (f32x4){0.f, 0.f, 0.f, 0.f};
      z = __builtin_amdgcn_mfma_f32_16x16x32_bf16(ka[t4][0], bq0, z, 0, 0, 0);
      s[t4] = __builtin_amdgcn_mfma_f32_16x16x32_bf16(ka[t4][1], bq1, z, 0, 0, 0);
    }

    // ---- p = exp2(s*c), diagonal mask, in-lane row-sum, P->LDS ----
    const bool diag = (kt == qt);
    const int kc0 = kt * 64 + quad * 4;
    float rs = 0.f;
#pragma unroll
    for (int t4 = 0; t4 < 4; ++t4) {
      float p[4];
#pragma unroll
      for (int i = 0; i < 4; ++i) {
        float e = EXP2(s[t4][i] * SCALE_LOG2E);
        if (diag) e = (kc0 + t4 * 16 + i > qrow) ? 0.f : e;
        p[i] = e;
        rs += e;
      }
      uint2 dw;
      dw.x = pack_bf2(p[0], p[1]);
      dw.y = pack_bf2(p[2], p[3]);
      const int cg = t4 * 2 + (quad >> 1);
      *(uint2*)(Pw + lq * 64 + ((cg ^ l3) * 8) + (quad & 1) * 4) = dw;
    }
    l_sum += rs;

    // ---- O^T += V^T · P^T ----
    const unsigned short* Vb = Vs[buf];
#pragma unroll
    for (int kh = 0; kh < 2; ++kh) {
      short8 bp = *(const short8*)(Pw + lq * 64 + (((kh * 4 + quad) ^ l3) * 8));
#pragma unroll
      for (int nd = 0; nd < 4; ++nd) {
        short8 va = *(const short8*)(Vb + (nd * 16 + lq) * 64 + (((kh * 4 + quad) ^ l3) * 8));
        o_acc[nd] = __builtin_amdgcn_mfma_f32_16x16x32_bf16(va, bp, o_acc[nd], 0, 0, 0);
      }
    }

    asm volatile("s_barrier" ::: "memory");
  }

  // final cross-quad row-sum reduction
  l_sum += __shfl_xor(l_sum, 16);
  l_sum += __shfl_xor(l_sum, 32);

  const int b = bh >> 4, h = bh & 15;
  const float inv = 1.0f / l_sum;
  const int n = qrow >> 1, p = qrow & 1;
  unsigned short* dst = Aov + ((size_t)(b * 1024 + n)) * 2048 + (h * 2 + p) * 64;
#pragma unroll
  for (int nd = 0; nd < 4; ++nd) {
    uint2 dw;
    dw.x = pack_bf2(o_acc[nd][0] * inv, o_acc[nd][1] * inv);
    dw.y = pack_bf2(o_acc[nd][2] * inv, o_acc[nd][3] * inv);
    *(uint2*)(dst + nd * 16 + quad * 4) = dw;
  }
}

// ---------------------------------------------------------------------------
extern "C" void kernel_launch(void* const* d_in, const int* in_sizes, int n_in,
                              void* d_out, int out_size, void* d_ws, size_t ws_size,
                              hipStream_t stream) {
  (void)in_sizes; (void)n_in; (void)out_size; (void)ws_size;
  const float* x    = (const float*)d_in[0];
  const float* Wq   = (const float*)d_in[1];
  const float* Wk   = (const float*)d_in[2];
  const float* Wv   = (const float*)d_in[3];
  const float* Wo   = (const float*)d_in[4];
  const float* aq   = (const float*)d_in[5];
  const float* ak   = (const float*)d_in[6];
  const float* av   = (const float*)d_in[7];
  const float* coll = (const float*)d_in[8];
  float* out = (float*)d_out;

  char* ws = (char*)d_ws;
  const size_t MB = 1024 * 1024;
  unsigned short* Xb    = (unsigned short*)(ws);            // 4 MB  [0,4)
  unsigned short* Woeff = (unsigned short*)(ws + 4 * MB);   // 4 MB  [4,8)
  unsigned short* Weff  = (unsigned short*)(ws + 8 * MB);   // 12 MB [8,20)
  unsigned short* Qv    = (unsigned short*)(ws + 20 * MB);  // 8 MB  [20,28)
  unsigned short* Kv    = (unsigned short*)(ws + 28 * MB);  // 8 MB  [28,36)
  unsigned short* Vt    = (unsigned short*)(ws + 36 * MB);  // 8 MB  [36,44)
  // Weff dead after QKV GEMM; reuse:
  unsigned short* Aov   = (unsigned short*)(ws + 8 * MB);   // 8 MB  [8,16)

  cast_f32_bf16<<<dim3(1024), dim3(256), 0, stream>>>(x, Xb, (B_ * S_ * HID_) / 4);
  weff_kernel<<<dim3(64, 3), dim3(256), 0, stream>>>(Wq, Wk, Wv, aq, ak, av, Weff);
  qkv_gemm<<<dim3(16, 16, 3), dim3(256), 0, stream>>>(Xb, Weff, Qv, Kv, Vt);
  attn_kernel<<<dim3(32, 32), dim3(256), 0, stream>>>(Qv, Kv, Vt, Aov);
  woeff_kernel<<<dim3(1024), dim3(256), 0, stream>>>(Wo, coll, Woeff);
  gemm64<<<dim3(32, 8), dim3(256), 0, stream>>>(
      Aov, Woeff, 2048, 1024, 2048, out);
}